// Round 5
// baseline (1723.076 us; speedup 1.0000x reference)
//
#include <hip/hip_runtime.h>
#include <hip/hip_bf16.h>

#define D 96
#define ASTR 104       // LDS bf16 row stride (halves): 208B, 16B-aligned, 2-way banks (free)
#define WSTR 104
#define NSCAT 64       // scatter blocks
#define MAXBUK 832     // >= nbuk = ceil(50000/64) = 782

typedef __attribute__((ext_vector_type(8))) short short8;   // 8 bf16 = 4 VGPRs
typedef __attribute__((ext_vector_type(4))) float f32x4v;   // MFMA accumulator

__device__ inline float blo(unsigned u) { return __uint_as_float(u << 16); }
__device__ inline float bhi(unsigned u) { return __uint_as_float(u & 0xffff0000u); }

// ---------------- copy x into out[:, 0:96] and bf16 mirror ----------------
__global__ void k_copyx(const float* __restrict__ x, float* __restrict__ out,
                        __hip_bfloat16* __restrict__ ha, int n) {
    int idx = blockIdx.x * blockDim.x + threadIdx.x;   // n*24 float4s
    if (idx >= n * 24) return;
    int r = idx / 24, c = idx - r * 24;
    float4 v = ((const float4*)x)[r * 24 + c];
    ((float4*)out)[r * 96 + c] = v;
    union { __hip_bfloat16 hh[4]; uint2 u; } p;
    p.hh[0] = __float2bfloat16(v.x); p.hh[1] = __float2bfloat16(v.y);
    p.hh[2] = __float2bfloat16(v.z); p.hh[3] = __float2bfloat16(v.w);
    ((uint2*)ha)[r * 24 + c] = p.u;
}

// ---------------- weight prep: fp32 [k][n] -> bf16 transposed [n][k] stride 104 ----------------
__global__ void k_prep(const float* __restrict__ w10, const float* __restrict__ w20,
                       const float* __restrict__ w11, const float* __restrict__ w21,
                       const float* __restrict__ w12, const float* __restrict__ w22,
                       __hip_bfloat16* __restrict__ wTg) {
    int idx = blockIdx.x * blockDim.x + threadIdx.x;   // 6*9216
    if (idx >= 6 * 9216) return;
    int m = idx / 9216, i = idx - m * 9216;
    int k = i / 96, nn = i - k * 96;
    const float* W;
    switch (m) {
        case 0: W = w10; break; case 1: W = w20; break;
        case 2: W = w11; break; case 3: W = w21; break;
        case 4: W = w12; break; default: W = w22; break;
    }
    wTg[(size_t)m * (96 * WSTR) + nn * WSTR + k] = __float2bfloat16(W[k * 96 + nn]);
}

// ---------------- per-(block,bucket) histogram: cnt[k*nbuk + b] ----------------
__global__ __launch_bounds__(256) void k_bcount(const int* __restrict__ dst,
                                                int* __restrict__ cnt, int E, int nbuk) {
    __shared__ int h[MAXBUK];
    int tid = threadIdx.x, k = blockIdx.x;
    for (int i = tid; i < nbuk; i += 256) h[i] = 0;
    __syncthreads();
    int chunk = (E + NSCAT - 1) / NSCAT;
    int e0 = k * chunk, e1 = min(e0 + chunk, E);
    for (int e = e0 + tid; e < e1; e += 256)
        atomicAdd(&h[dst[e] >> 6], 1);
    __syncthreads();
    for (int i = tid; i < nbuk; i += 256) cnt[k * nbuk + i] = h[i];   // single-writer rows
}

// ---------------- padded exclusive scan over M = nbuk*64 counters (bucket-major) ----------------
// element m: b = m>>6, k = m&63; value = pad16(cnt[k*nbuk + b])
__global__ __launch_bounds__(256) void k_scanA(const int* __restrict__ cnt,
                                               int* __restrict__ base,
                                               int* __restrict__ bsum, int nbuk) {
    __shared__ int ts[256];
    int j = blockIdx.x, t = threadIdx.x;
    int m0 = j * nbuk;                         // block covers nbuk consecutive bucket-major idx
    int v[4]; int s = 0;
    #pragma unroll
    for (int i = 0; i < 4; i++) {
        int ml = t * 4 + i; int p = 0;
        if (ml < nbuk) {
            int m = m0 + ml; int b = m >> 6, k = m & 63;
            p = (cnt[k * nbuk + b] + 15) & ~15;   // pad to 16 entries = 64B
        }
        v[i] = p; s += p;
    }
    ts[t] = s;
    __syncthreads();
    for (int off = 1; off < 256; off <<= 1) {
        int u = (t >= off) ? ts[t - off] : 0;
        __syncthreads();
        ts[t] += u;
        __syncthreads();
    }
    int run = ts[t] - s;                       // exclusive thread prefix
    #pragma unroll
    for (int i = 0; i < 4; i++) {
        int ml = t * 4 + i;
        if (ml < nbuk) { base[m0 + ml] = run; run += v[i]; }
    }
    if (t == 255) bsum[j] = ts[255];
}

__global__ __launch_bounds__(256) void k_scanC(int* __restrict__ base,
                                               const int* __restrict__ bsum, int nbuk) {
    __shared__ int bs[NSCAT];
    int j = blockIdx.x, t = threadIdx.x;
    if (t < NSCAT) bs[t] = bsum[t];
    __syncthreads();
    int off = 0;
    for (int i = 0; i < j; i++) off += bs[i];
    #pragma unroll
    for (int i = 0; i < 4; i++) {
        int ml = t * 4 + i;
        if (ml < nbuk) base[j * nbuk + ml] += off;
    }
}

// ---------------- scatter: packed 4B records into per-(bucket,block) padded segments ----------------
__global__ __launch_bounds__(1024) void k_bscatter(const int* __restrict__ src,
                                                   const int* __restrict__ dst,
                                                   const int* __restrict__ base,
                                                   unsigned* __restrict__ epair,
                                                   int E, int nbuk) {
    __shared__ int cur[MAXBUK];
    int k = blockIdx.x, tid = threadIdx.x;
    for (int i = tid; i < nbuk; i += 1024) cur[i] = base[i * 64 + k];
    __syncthreads();
    int chunk = (E + NSCAT - 1) / NSCAT;
    int e0 = k * chunk, e1 = min(e0 + chunk, E);
    for (int e = e0 + tid; e < e1; e += 1024) {
        int d = dst[e];
        int p = atomicAdd(&cur[d >> 6], 1);                 // LDS atomic, block-private
        epair[p] = ((unsigned)src[e] << 6) | (unsigned)(d & 63);
    }
}

// ---------------- fused layer: aggregate (gather + LDS f32 atomics) + MFMA MLP ----------------
// block = bucket = 64 nodes. LDS: acc fp32 64x96 (overlaid by wS), aT bf16, seg meta. ~38KB -> 4 blk/CU.
__global__ __launch_bounds__(256, 4) void k_fused(const __hip_bfloat16* __restrict__ hin,
                                                  const unsigned* __restrict__ epair,
                                                  const int* __restrict__ base,
                                                  const int* __restrict__ cnt,
                                                  const __hip_bfloat16* __restrict__ w1t,
                                                  const float* __restrict__ B1,
                                                  const __hip_bfloat16* __restrict__ w2t,
                                                  const float* __restrict__ B2,
                                                  __hip_bfloat16* __restrict__ hout,
                                                  float* __restrict__ out,
                                                  int n, int nbuk, int ocol) {
    __shared__ __align__(16) char smem[24576 + 13312 + 512];
    float* acc = (float*)smem;                       // 64*96 f32 (dead after convert)
    short* wS  = (short*)smem;                       // 96*104 bf16 (overlays acc)
    short* aT  = (short*)(smem + 24576);             // 64*104 bf16
    int* segb  = (int*)(smem + 24576 + 13312);       // 64
    int* segc  = (int*)(smem + 24576 + 13312 + 256); // 64

    const int tid = threadIdx.x;
    const int bkt = blockIdx.x;
    const int row0 = bkt * 64;

    if (tid < 64) {
        segb[tid] = base[bkt * 64 + tid];
        segc[tid] = cnt[tid * nbuk + bkt];
    }
    // self-term init (eps=0): acc[r][:] = hin[row0+r][:]; zero for rows >= n
    const uint2* hin2 = (const uint2*)hin;
    for (int idx = tid; idx < 64 * 24; idx += 256) {
        int r = idx / 24, c = idx - r * 24;
        int gr = row0 + r;
        float f0 = 0.f, f1 = 0.f, f2 = 0.f, f3 = 0.f;
        if (gr < n) {
            uint2 u = hin2[(size_t)gr * 24 + c];
            f0 = blo(u.x); f1 = bhi(u.x); f2 = blo(u.y); f3 = bhi(u.y);
        }
        float* ap = &acc[r * 96 + c * 4];
        ap[0] = f0; ap[1] = f1; ap[2] = f2; ap[3] = f3;
    }
    __syncthreads();

    // gather + accumulate: 8 groups of 32 lanes; group g handles segments g, g+8, ...
    {
        int g = tid >> 5, lane = tid & 31;
        if (lane < 24) {
            for (int k = g; k < 64; k += 8) {
                int sb = segb[k], sc = segc[k];
                int j = 0;
                for (; j + 4 <= sc; j += 4) {
                    unsigned v0 = epair[sb + j], v1 = epair[sb + j + 1];
                    unsigned v2 = epair[sb + j + 2], v3 = epair[sb + j + 3];
                    uint2 a0 = hin2[(size_t)(v0 >> 6) * 24 + lane];
                    uint2 a1 = hin2[(size_t)(v1 >> 6) * 24 + lane];
                    uint2 a2 = hin2[(size_t)(v2 >> 6) * 24 + lane];
                    uint2 a3 = hin2[(size_t)(v3 >> 6) * 24 + lane];
                    float* p0 = &acc[(int)(v0 & 63) * 96 + lane * 4];
                    float* p1 = &acc[(int)(v1 & 63) * 96 + lane * 4];
                    float* p2 = &acc[(int)(v2 & 63) * 96 + lane * 4];
                    float* p3 = &acc[(int)(v3 & 63) * 96 + lane * 4];
                    atomicAdd(p0 + 0, blo(a0.x)); atomicAdd(p0 + 1, bhi(a0.x));
                    atomicAdd(p0 + 2, blo(a0.y)); atomicAdd(p0 + 3, bhi(a0.y));
                    atomicAdd(p1 + 0, blo(a1.x)); atomicAdd(p1 + 1, bhi(a1.x));
                    atomicAdd(p1 + 2, blo(a1.y)); atomicAdd(p1 + 3, bhi(a1.y));
                    atomicAdd(p2 + 0, blo(a2.x)); atomicAdd(p2 + 1, bhi(a2.x));
                    atomicAdd(p2 + 2, blo(a2.y)); atomicAdd(p2 + 3, bhi(a2.y));
                    atomicAdd(p3 + 0, blo(a3.x)); atomicAdd(p3 + 1, bhi(a3.x));
                    atomicAdd(p3 + 2, blo(a3.y)); atomicAdd(p3 + 3, bhi(a3.y));
                }
                for (; j < sc; j++) {
                    unsigned v = epair[sb + j];
                    uint2 a = hin2[(size_t)(v >> 6) * 24 + lane];
                    float* p = &acc[(int)(v & 63) * 96 + lane * 4];
                    atomicAdd(p + 0, blo(a.x)); atomicAdd(p + 1, bhi(a.x));
                    atomicAdd(p + 2, blo(a.y)); atomicAdd(p + 3, bhi(a.y));
                }
            }
        }
    }
    __syncthreads();

    // convert acc -> bf16 aT (row-major, k-contiguous)
    for (int idx = tid; idx < 64 * 24; idx += 256) {
        int r = idx / 24, c = idx - r * 24;
        const float* ap = &acc[r * 96 + c * 4];
        union { __hip_bfloat16 hh[4]; uint2 u; } p;
        p.hh[0] = __float2bfloat16(ap[0]); p.hh[1] = __float2bfloat16(ap[1]);
        p.hh[2] = __float2bfloat16(ap[2]); p.hh[3] = __float2bfloat16(ap[3]);
        *(uint2*)&aT[r * ASTR + c * 4] = p.u;
    }
    __syncthreads();                                 // acc dead from here

    // stage W1 into wS (overlays acc)
    {
        const unsigned* wsrc = (const unsigned*)w1t;
        unsigned* wdst = (unsigned*)wS;
        for (int idx = tid; idx < 96 * WSTR / 2; idx += 256) wdst[idx] = wsrc[idx];
    }
    __syncthreads();

    const int lane = tid & 63;
    const int wv = __builtin_amdgcn_readfirstlane(tid >> 6);
    const int wr0 = wv * 16;
    const int quad = lane >> 4;
    const int r = lane & 15;

    short8 af[3];
    #pragma unroll
    for (int ksi = 0; ksi < 3; ksi++)
        af[ksi] = *(const short8*)&aT[(wr0 + r) * ASTR + ksi * 32 + quad * 8];

    // ---- pass 1 ----
    f32x4v c1[6];
    #pragma unroll
    for (int nt = 0; nt < 6; nt++) {
        f32x4v c = {0.f, 0.f, 0.f, 0.f};
        #pragma unroll
        for (int ksi = 0; ksi < 3; ksi++) {
            short8 bfr = *(const short8*)&wS[(nt * 16 + r) * WSTR + ksi * 32 + quad * 8];
            c = __builtin_amdgcn_mfma_f32_16x16x32_bf16(af[ksi], bfr, c, 0, 0, 0);
        }
        c1[nt] = c;
    }
    __syncthreads();                                 // W1 reads done

    // y1 = relu(c1 + b1) -> own band of aT; restage W2
    #pragma unroll
    for (int nt = 0; nt < 6; nt++) {
        float bv = B1[nt * 16 + r];
        #pragma unroll
        for (int i = 0; i < 4; i++) {
            float y = fmaxf(c1[nt][i] + bv, 0.f);
            __hip_bfloat16 hb = __float2bfloat16(y);
            aT[(wr0 + quad * 4 + i) * ASTR + nt * 16 + r] = *(short*)&hb;
        }
    }
    {
        const unsigned* wsrc = (const unsigned*)w2t;
        unsigned* wdst = (unsigned*)wS;
        for (int idx = tid; idx < 96 * WSTR / 2; idx += 256) wdst[idx] = wsrc[idx];
    }
    __syncthreads();

    // ---- pass 2 ----
    short8 af2[3];
    #pragma unroll
    for (int ksi = 0; ksi < 3; ksi++)
        af2[ksi] = *(const short8*)&aT[(wr0 + r) * ASTR + ksi * 32 + quad * 8];

    #pragma unroll
    for (int nt = 0; nt < 6; nt++) {
        f32x4v c = {0.f, 0.f, 0.f, 0.f};
        #pragma unroll
        for (int ksi = 0; ksi < 3; ksi++) {
            short8 bfr = *(const short8*)&wS[(nt * 16 + r) * WSTR + ksi * 32 + quad * 8];
            c = __builtin_amdgcn_mfma_f32_16x16x32_bf16(af2[ksi], bfr, c, 0, 0, 0);
        }
        float bv = B2[nt * 16 + r];
        int col = nt * 16 + r;
        #pragma unroll
        for (int i = 0; i < 4; i++) {
            int gr = row0 + quad * 4 + i + wr0;
            if (gr < n) {
                float v = c[i] + bv;
                out[(size_t)gr * 384 + ocol + col] = v;
                hout[(size_t)gr * D + col] = __float2bfloat16(v);
            }
        }
    }
}

extern "C" void kernel_launch(void* const* d_in, const int* in_sizes, int n_in,
                              void* d_out, int out_size, void* d_ws, size_t ws_size,
                              hipStream_t stream) {
    const float* x = (const float*)d_in[0];
    const int* ei = (const int*)d_in[1];
    const int n = in_sizes[0] / D;           // 50000
    const int E = in_sizes[1] / 2;           // 800000
    const int* src = ei;
    const int* dst = ei + E;
    float* out = (float*)d_out;

    const int nbuk = (n + 63) >> 6;          // 782
    const int M = nbuk * 64;                 // 50048

    // workspace layout (byte offsets, 16B-aligned)
    char* ws = (char*)d_ws;
    __hip_bfloat16* ha  = (__hip_bfloat16*)ws;                   // n*96 halves = 9.6 MB
    __hip_bfloat16* hb  = (__hip_bfloat16*)(ws + 9600000);       // 9.6 MB
    __hip_bfloat16* wTg = (__hip_bfloat16*)(ws + 19200000);      // ~120 KB
    int* cnt   = (int*)(ws + 19320064);                          // M ints
    int* base  = (int*)(ws + 19520256);                          // M ints
    int* bsum  = (int*)(ws + 19720448);                          // 64 ints
    unsigned* epair = (unsigned*)(ws + 19720704);                // <= E + M*15 ints ~ 6.2 MB

    // out[:,0:96] = x ; ha = bf16(x)
    k_copyx<<<(n * 24 + 255) / 256, 256, 0, stream>>>(x, out, ha, n);

    // weights -> bf16 transposed
    k_prep<<<(6 * 9216 + 255) / 256, 256, 0, stream>>>(
        (const float*)d_in[2], (const float*)d_in[4],
        (const float*)d_in[6], (const float*)d_in[8],
        (const float*)d_in[10], (const float*)d_in[12], wTg);

    // bucket sort (once; shared by all 3 layers)
    k_bcount<<<NSCAT, 256, 0, stream>>>(dst, cnt, E, nbuk);
    k_scanA<<<NSCAT, 256, 0, stream>>>(cnt, base, bsum, nbuk);
    k_scanC<<<NSCAT, 256, 0, stream>>>(base, bsum, nbuk);
    k_bscatter<<<NSCAT, 1024, 0, stream>>>(src, dst, base, epair, E, nbuk);

    // 3 fused layers, double-buffered h
    const __hip_bfloat16* hbuf_in[3]  = { ha, hb, ha };
    __hip_bfloat16*       hbuf_out[3] = { hb, ha, hb };
    for (int l = 0; l < 3; l++) {
        const float* B1 = (const float*)d_in[3 + 4 * l];
        const float* B2 = (const float*)d_in[5 + 4 * l];
        const __hip_bfloat16* w1t = wTg + (size_t)(2 * l) * (96 * WSTR);
        const __hip_bfloat16* w2t = wTg + (size_t)(2 * l + 1) * (96 * WSTR);
        k_fused<<<nbuk, 256, 0, stream>>>(hbuf_in[l], epair, base, cnt, w1t, B1, w2t, B2,
                                          hbuf_out[l], out, n, nbuk, (l + 1) * D);
    }
}